// Round 1
// baseline (2307.898 us; speedup 1.0000x reference)
//
#include <hip/hip_runtime.h>
#include <hip/hip_fp16.h>

typedef _Float16 half8 __attribute__((ext_vector_type(8)));
typedef float floatx4 __attribute__((ext_vector_type(4)));
typedef int intx4 __attribute__((ext_vector_type(4)));

#define NB 256   // batch
#define ND 256   // D
#define NL 256   // L (time)
#define NH 512   // H

// ---------------- Kernel 1: x_proj[b,d] = sum_l x[b,d,l] * Wx[l] ----------------
__global__ void k_xproj(const float* __restrict__ x, const float* __restrict__ Wattn,
                        float* __restrict__ xproj) {
    __shared__ float wx[NL];
    const int tid = threadIdx.x;
    wx[tid] = Wattn[2 * NH + tid];   // blockDim = 256 == NL
    __syncthreads();
    const int wid = tid >> 6, lane = tid & 63;
    const int row = blockIdx.x * 4 + wid;          // row = b*ND + d, 65536 rows
    const float4 v = ((const float4*)(x + (size_t)row * NL))[lane];
    float s = v.x * wx[lane * 4] + v.y * wx[lane * 4 + 1] +
              v.z * wx[lane * 4 + 2] + v.w * wx[lane * 4 + 3];
    #pragma unroll
    for (int off = 32; off; off >>= 1) s += __shfl_down(s, off);
    if (lane == 0) xproj[row] = s;
}

// ---------------- Kernel 2: attn[b,:] = softmax(x_proj[b,:]) ----------------
__global__ void k_softmax(const float* __restrict__ xproj, float* __restrict__ attn) {
    const int b = blockIdx.x, tid = threadIdx.x;
    __shared__ float red[8];
    float v = xproj[b * ND + tid];
    float m = v;
    #pragma unroll
    for (int off = 32; off; off >>= 1) m = fmaxf(m, __shfl_down(m, off));
    const int wid = tid >> 6, lane = tid & 63;
    if (lane == 0) red[wid] = m;
    __syncthreads();
    if (tid == 0) {
        float mm = fmaxf(fmaxf(red[0], red[1]), fmaxf(red[2], red[3]));
        red[4] = mm;
    }
    __syncthreads();
    const float e = expf(v - red[4]);
    float s = e;
    #pragma unroll
    for (int off = 32; off; off >>= 1) s += __shfl_down(s, off);
    if (lane == 0) red[wid] = s;
    __syncthreads();
    if (tid == 0) red[5] = red[0] + red[1] + red[2] + red[3];
    __syncthreads();
    attn[b * ND + tid] = e / red[5];
}

// ---- Kernel 3: ws[b,t,d] = attn[b,d]*x[b,d,t] (fp32 out) ; w16[t,b,d] = fp16(same) ----
__global__ void k_trans(const float* __restrict__ x, const float* __restrict__ attn,
                        float* __restrict__ ws_out, _Float16* __restrict__ w16) {
    __shared__ float tile[64][65];
    const int bid = blockIdx.x;
    const int b = bid >> 4, ti = (bid >> 2) & 3, tj = bid & 3;
    const int tx = threadIdx.x & 63, ty = threadIdx.x >> 6;
    const int d0 = ti * 64, l0 = tj * 64;
    const float* xb = x + ((size_t)b * ND + d0) * NL + l0;
    #pragma unroll
    for (int r = ty; r < 64; r += 4) tile[r][tx] = xb[(size_t)r * NL + tx];
    __syncthreads();
    const float af = attn[b * ND + d0 + tx];
    #pragma unroll
    for (int r = ty; r < 64; r += 4) {
        const int tt = l0 + r;
        const float val = af * tile[tx][r];
        ws_out[((size_t)b * NL + tt) * ND + d0 + tx] = val;
        w16[((size_t)tt * NB + b) * ND + d0 + tx] = (_Float16)val;
    }
}

// ---------------- Kernel 4: weight conversion (hi/lo split for W_hh) ----------------
__global__ void k_wsplit(const float* __restrict__ Whh, const float* __restrict__ Wih,
                         _Float16* __restrict__ hi, _Float16* __restrict__ lo,
                         _Float16* __restrict__ wih16) {
    const int idx = blockIdx.x * 256 + threadIdx.x;   // 4096*256 = 1048576 = 4H*H
    const float w = Whh[idx];
    const _Float16 h = (_Float16)w;
    hi[idx] = h;
    lo[idx] = (_Float16)(w - (float)h);
    if (idx < 4 * NH * ND) wih16[idx] = (_Float16)Wih[idx];
}

// ---------------- Kernel 5: persistent LSTM recurrence ----------------
// grid = 256 wgs x 512 thr. wg (m = bid&15, hb = bid>>4):
//   rows b in [16m, 16m+16), gate cols j = g*512 + hb*32 + [0,32) for g=0..3
// group = 16 wgs sharing m; h exchanged via L3-coherent fp16 buffer + flag barrier.
__launch_bounds__(512, 2)
__global__ void k_recur(const _Float16* __restrict__ whhHi, const _Float16* __restrict__ whhLo,
                        const _Float16* __restrict__ wih16, const _Float16* __restrict__ w16,
                        const float* __restrict__ b_ih, const float* __restrict__ b_hh,
                        _Float16* __restrict__ h16,   // [2][NB][NH]
                        int* __restrict__ flags,      // [16][16]
                        float* __restrict__ out_hs)   // [NB][NL][NH]
{
    __shared__ char smem[32768];
    // [0,16384)      : hLDS  [16][512] fp16, 16B-granule XOR swizzle
    // [16384,24576)  : wLDS  [16][256] fp16, same swizzle
    // [24576,32768)  : accL  float[8][16][16]
    const int tid = threadIdx.x;
    const int wid = tid >> 6, lane = tid & 63;
    const int bid = blockIdx.x;
    const int m = bid & 15, hb = bid >> 4;
    const int b0 = m * 16;
    const int gate = wid >> 1, half = wid & 1;
    const int jb = gate * 512 + hb * 32 + half * 16;

    // --- persistent B fragments (live across whole time loop) ---
    half8 bhhH[16], bhhL[16], bihF[8];
    const int bcol = jb + (lane & 15);
    const int krow = (lane >> 4) * 8;
    #pragma unroll
    for (int kk = 0; kk < 16; ++kk) {
        bhhH[kk] = *(const half8*)(whhHi + (size_t)bcol * NH + kk * 32 + krow);
        bhhL[kk] = *(const half8*)(whhLo + (size_t)bcol * NH + kk * 32 + krow);
    }
    #pragma unroll
    for (int kk = 0; kk < 8; ++kk)
        bihF[kk] = *(const half8*)(wih16 + (size_t)bcol * ND + kk * 32 + krow);

    // --- cell-phase thread mapping: one (b, h_idx) per thread ---
    const int bl = tid >> 5, hl = tid & 31;
    float bias_[4];
    #pragma unroll
    for (int g = 0; g < 4; ++g) {
        const int j = g * 512 + hb * 32 + hl;
        bias_[g] = b_ih[j] + b_hh[j];
    }
    float c = 0.f;
    float* hsOut = out_hs + (size_t)(b0 + bl) * NL * NH + hb * 32 + hl;
    _Float16* hWr = h16 + (size_t)(b0 + bl) * NH + hb * 32 + hl;  // + buf*NB*NH

    // A-frag read geometry
    const int arow = lane & 15;
    const int aq = (lane >> 4) * 16;     // byte offset of 16B chunk within 64B k-block
    const int aswz = (arow & 7) << 4;

    #pragma unroll 1
    for (int t = 0; t < NL; ++t) {
        // ---- stage h16[t&1] (16KB, L3-coherent loads) + w16[t] (8KB, cached) ----
        {
            const char* hsrc = (const char*)(h16 + (size_t)(t & 1) * NB * NH + (size_t)b0 * NH);
            const void* p0 = hsrc + tid * 16;
            const void* p1 = hsrc + tid * 16 + 8192;
            intx4 d0, d1;
            asm volatile(
                "global_load_dwordx4 %0, %2, off sc0 sc1\n\t"
                "global_load_dwordx4 %1, %3, off sc0 sc1\n\t"
                "s_waitcnt vmcnt(0)"
                : "=v"(d0), "=v"(d1) : "v"(p0), "v"(p1) : "memory");
            const int r0 = tid >> 6;               // 1024B per row
            const int r1 = (tid + 512) >> 6;
            *(intx4*)(smem + ((tid * 16) ^ ((r0 & 7) << 4))) = d0;
            *(intx4*)(smem + ((tid * 16 + 8192) ^ ((r1 & 7) << 4))) = d1;

            const char* wsrc = (const char*)(w16 + ((size_t)t * NB + b0) * ND);
            const intx4 wd = *(const intx4*)(wsrc + tid * 16);
            const int wr = tid >> 5;               // 512B per row
            *(intx4*)(smem + 16384 + ((tid * 16) ^ ((wr & 7) << 4))) = wd;
        }
        __syncthreads();

        // ---- GEMM: gates tile (16 b x 16 j), K = 512 (h, split-W) + 256 (w) ----
        floatx4 accA = {0.f, 0.f, 0.f, 0.f};
        floatx4 accB = {0.f, 0.f, 0.f, 0.f};
        floatx4 accC = {0.f, 0.f, 0.f, 0.f};
        #pragma unroll
        for (int kk = 0; kk < 16; ++kk) {
            const int aaddr = ((arow << 10) + (kk << 6) + aq) ^ aswz;
            const half8 a = *(const half8*)(smem + aaddr);
            accA = __builtin_amdgcn_mfma_f32_16x16x32_f16(a, bhhH[kk], accA, 0, 0, 0);
            accB = __builtin_amdgcn_mfma_f32_16x16x32_f16(a, bhhL[kk], accB, 0, 0, 0);
        }
        #pragma unroll
        for (int kk = 0; kk < 8; ++kk) {
            const int waddr = 16384 + (((arow << 9) + (kk << 6) + aq) ^ aswz);
            const half8 a = *(const half8*)(smem + waddr);
            accC = __builtin_amdgcn_mfma_f32_16x16x32_f16(a, bihF[kk], accC, 0, 0, 0);
        }
        const floatx4 f = (accA + accB) + accC;

        // ---- exchange acc tiles through LDS ----
        {
            float* accL = (float*)(smem + 24576);
            const int colw = lane & 15, rowq = (lane >> 4) * 4;
            #pragma unroll
            for (int r = 0; r < 4; ++r)
                accL[wid * 256 + (rowq + r) * 16 + colw] = f[r];
        }
        __syncthreads();

        // ---- LSTM cell (one (b, h_idx) per thread; c in register) ----
        {
            const float* accL = (const float*)(smem + 24576);
            const int hq = hl >> 4, cidx = hl & 15;
            const int off = bl * 16 + cidx;
            const float pi = accL[(0 + hq) * 256 + off] + bias_[0];
            const float pf = accL[(2 + hq) * 256 + off] + bias_[1];
            const float pg = accL[(4 + hq) * 256 + off] + bias_[2];
            const float po = accL[(6 + hq) * 256 + off] + bias_[3];
            const float si = 1.f / (1.f + __expf(-pi));
            const float sf = 1.f / (1.f + __expf(-pf));
            const float so = 1.f / (1.f + __expf(-po));
            float e2 = __expf(-2.f * fabsf(pg));
            float tg = (1.f - e2) / (1.f + e2);
            tg = (pg < 0.f) ? -tg : tg;
            c = sf * c + si * tg;
            float e2c = __expf(-2.f * fabsf(c));
            float tc = (1.f - e2c) / (1.f + e2c);
            tc = (c < 0.f) ? -tc : tc;
            const float h2 = so * tc;
            hsOut[(size_t)t * NH] = h2;
            const _Float16 hh = (_Float16)h2;
            const unsigned int hv = (unsigned int)__builtin_bit_cast(unsigned short, hh);
            const void* hp = hWr + (size_t)((t + 1) & 1) * NB * NH;
            asm volatile("global_store_short %0, %1, off sc0 sc1"
                         :: "v"(hp), "v"(hv) : "memory");
        }

        // ---- group barrier (16 wgs sharing m) ----
        if (t < NL - 1) {
            __syncthreads();   // drains all wg stores (vmcnt 0 before s_barrier)
            if (tid == 0)
                __hip_atomic_store(&flags[(m << 4) + hb], t + 1,
                                   __ATOMIC_RELEASE, __HIP_MEMORY_SCOPE_AGENT);
            if (wid == 0) {
                const int idx = (m << 4) + (lane & 15);
                const int target = t + 1;
                while (true) {
                    const int v = __hip_atomic_load(&flags[idx], __ATOMIC_ACQUIRE,
                                                    __HIP_MEMORY_SCOPE_AGENT);
                    if (__all(v >= target)) break;
                    __builtin_amdgcn_s_sleep(2);
                }
            }
            __syncthreads();
        }
    }
}

extern "C" void kernel_launch(void* const* d_in, const int* in_sizes, int n_in,
                              void* d_out, int out_size, void* d_ws, size_t ws_size,
                              hipStream_t stream) {
    const float* x     = (const float*)d_in[0];
    const float* Wattn = (const float*)d_in[1];
    // d_in[2] = b_attn : provably unused (softmax shift invariance)
    const float* Wih   = (const float*)d_in[3];
    const float* Whh   = (const float*)d_in[4];
    const float* bih   = (const float*)d_in[5];
    const float* bhh   = (const float*)d_in[6];

    float* ws_out = (float*)d_out;                                 // [B][L][D]
    float* hs_out = ws_out + (size_t)NB * NL * ND;                 // [B][L][H]

    char* ws = (char*)d_ws;
    int*      flags = (int*)(ws + 0);                              // 1 KB
    float*    attn  = (float*)(ws + 4096);                         // 256 KB
    float*    xproj = (float*)(ws + 4096 + 262144);                // 256 KB
    _Float16* h16   = (_Float16*)(ws + 1048576);                   // 2 x 256 KB
    _Float16* whhHi = (_Float16*)(ws + 2097152);                   // 2 MB
    _Float16* whhLo = (_Float16*)(ws + 2097152 + 2097152);         // 2 MB
    _Float16* wih16 = (_Float16*)(ws + 6291456);                   // 1 MB
    _Float16* w16   = (_Float16*)(ws + 8388608);                   // 33.5 MB

    hipMemsetAsync(flags, 0, 4096, stream);
    hipMemsetAsync(h16, 0, (size_t)NB * NH * sizeof(_Float16), stream);  // buf0 = h(0)

    k_xproj  <<<16384, 256, 0, stream>>>(x, Wattn, xproj);
    k_softmax<<<256,   256, 0, stream>>>(xproj, attn);
    k_trans  <<<4096,  256, 0, stream>>>(x, attn, ws_out, w16);
    k_wsplit <<<4096,  256, 0, stream>>>(Whh, Wih, whhHi, whhLo, wih16);
    k_recur  <<<256,   512, 0, stream>>>(whhHi, whhLo, wih16, w16, bih, bhh,
                                         h16, flags, hs_out);
}

// Round 2
// 721.774 us; speedup vs baseline: 3.1975x; 3.1975x over previous
//
#include <hip/hip_runtime.h>
#include <hip/hip_fp16.h>

typedef _Float16 half8 __attribute__((ext_vector_type(8)));
typedef float floatx4 __attribute__((ext_vector_type(4)));
typedef int intx4 __attribute__((ext_vector_type(4)));

#define NB 256   // batch
#define ND 256   // D
#define NL 256   // L (time)
#define NH 512   // H

// ---------------- Kernel 1: x_proj[b,d] = sum_l x[b,d,l] * Wx[l] ----------------
__global__ void k_xproj(const float* __restrict__ x, const float* __restrict__ Wattn,
                        float* __restrict__ xproj) {
    __shared__ float wx[NL];
    const int tid = threadIdx.x;
    wx[tid] = Wattn[2 * NH + tid];   // blockDim = 256 == NL
    __syncthreads();
    const int wid = tid >> 6, lane = tid & 63;
    const int row = blockIdx.x * 4 + wid;          // row = b*ND + d, 65536 rows
    const float4 v = ((const float4*)(x + (size_t)row * NL))[lane];
    float s = v.x * wx[lane * 4] + v.y * wx[lane * 4 + 1] +
              v.z * wx[lane * 4 + 2] + v.w * wx[lane * 4 + 3];
    #pragma unroll
    for (int off = 32; off; off >>= 1) s += __shfl_down(s, off);
    if (lane == 0) xproj[row] = s;
}

// ---------------- Kernel 2: attn[b,:] = softmax(x_proj[b,:]) ----------------
__global__ void k_softmax(const float* __restrict__ xproj, float* __restrict__ attn) {
    const int b = blockIdx.x, tid = threadIdx.x;
    __shared__ float red[8];
    float v = xproj[b * ND + tid];
    float m = v;
    #pragma unroll
    for (int off = 32; off; off >>= 1) m = fmaxf(m, __shfl_down(m, off));
    const int wid = tid >> 6, lane = tid & 63;
    if (lane == 0) red[wid] = m;
    __syncthreads();
    if (tid == 0) {
        float mm = fmaxf(fmaxf(red[0], red[1]), fmaxf(red[2], red[3]));
        red[4] = mm;
    }
    __syncthreads();
    const float e = expf(v - red[4]);
    float s = e;
    #pragma unroll
    for (int off = 32; off; off >>= 1) s += __shfl_down(s, off);
    if (lane == 0) red[wid] = s;
    __syncthreads();
    if (tid == 0) red[5] = red[0] + red[1] + red[2] + red[3];
    __syncthreads();
    attn[b * ND + tid] = e / red[5];
}

// ---- Kernel 3: ws[b,t,d] = attn[b,d]*x[b,d,t] (fp32 out) ; w16[t,b,d] = fp16(same) ----
__global__ void k_trans(const float* __restrict__ x, const float* __restrict__ attn,
                        float* __restrict__ ws_out, _Float16* __restrict__ w16) {
    __shared__ float tile[64][65];
    const int bid = blockIdx.x;
    const int b = bid >> 4, ti = (bid >> 2) & 3, tj = bid & 3;
    const int tx = threadIdx.x & 63, ty = threadIdx.x >> 6;
    const int d0 = ti * 64, l0 = tj * 64;
    const float* xb = x + ((size_t)b * ND + d0) * NL + l0;
    #pragma unroll
    for (int r = ty; r < 64; r += 4) tile[r][tx] = xb[(size_t)r * NL + tx];
    __syncthreads();
    const float af = attn[b * ND + d0 + tx];
    #pragma unroll
    for (int r = ty; r < 64; r += 4) {
        const int tt = l0 + r;
        const float val = af * tile[tx][r];
        ws_out[((size_t)b * NL + tt) * ND + d0 + tx] = val;
        w16[((size_t)tt * NB + b) * ND + d0 + tx] = (_Float16)val;
    }
}

// ---------------- Kernel 4: weight conversion (hi/lo split for W_hh) ----------------
__global__ void k_wsplit(const float* __restrict__ Whh, const float* __restrict__ Wih,
                         _Float16* __restrict__ hi, _Float16* __restrict__ lo,
                         _Float16* __restrict__ wih16) {
    const int idx = blockIdx.x * 256 + threadIdx.x;   // 4096*256 = 1048576 = 4H*H
    const float w = Whh[idx];
    const _Float16 h = (_Float16)w;
    hi[idx] = h;
    lo[idx] = (_Float16)(w - (float)h);
    if (idx < 4 * NH * ND) wih16[idx] = (_Float16)Wih[idx];
}

// ---------------- Kernel 5: persistent LSTM recurrence ----------------
// grid = 256 wgs x 512 thr. wg (m = bid&15, hb = bid>>4):
//   rows b in [16m, 16m+16), gate cols j = g*512 + hb*32 + [0,32) for g=0..3
// group = 16 wgs sharing m. Sync protocol: raw sc0/sc1 loads/stores only
// (NO atomic builtins -> no buffer_inv / buffer_wbl2 cache maintenance).
// Producer: store h16 (sc0 sc1) -> vmcnt(0) -> barrier -> tid0 stores tag.
// Consumer: wave0 polls 16 tags (sc0 sc1 loads) until all >= t.
__launch_bounds__(512, 2)
__global__ void k_recur(const _Float16* __restrict__ whhHi, const _Float16* __restrict__ whhLo,
                        const _Float16* __restrict__ wih16, const _Float16* __restrict__ w16,
                        const float* __restrict__ b_ih, const float* __restrict__ b_hh,
                        _Float16* __restrict__ h16,   // [2][NB][NH]
                        int* __restrict__ flags,      // [16][16] step tags
                        float* __restrict__ out_hs)   // [NB][NL][NH]
{
    __shared__ char smem[40960];
    // [0,16384)      : hLDS  [16][512] fp16, 16B-granule XOR swizzle
    // [16384,32768)  : wLDS  2 x [16][256] fp16 (double-buffered), same swizzle
    // [32768,40960)  : accL  float[8][16][16]
    const int tid = threadIdx.x;
    const int wid = tid >> 6, lane = tid & 63;
    const int bid = blockIdx.x;
    const int m = bid & 15, hb = bid >> 4;
    const int b0 = m * 16;
    const int gate = wid >> 1, half = wid & 1;
    const int jb = gate * 512 + hb * 32 + half * 16;

    // --- persistent B fragments (live across whole time loop) ---
    half8 bhhH[16], bhhL[16], bihF[8];
    const int bcol = jb + (lane & 15);
    const int krow = (lane >> 4) * 8;
    #pragma unroll
    for (int kk = 0; kk < 16; ++kk) {
        bhhH[kk] = *(const half8*)(whhHi + (size_t)bcol * NH + kk * 32 + krow);
        bhhL[kk] = *(const half8*)(whhLo + (size_t)bcol * NH + kk * 32 + krow);
    }
    #pragma unroll
    for (int kk = 0; kk < 8; ++kk)
        bihF[kk] = *(const half8*)(wih16 + (size_t)bcol * ND + kk * 32 + krow);

    // --- cell-phase thread mapping: one (b, h_idx) per thread ---
    const int bl = tid >> 5, hl = tid & 31;
    float bias_[4];
    #pragma unroll
    for (int g = 0; g < 4; ++g) {
        const int j = g * 512 + hb * 32 + hl;
        bias_[g] = b_ih[j] + b_hh[j];
    }
    float c = 0.f;
    float* hsOut = out_hs + (size_t)(b0 + bl) * NL * NH + hb * 32 + hl;
    _Float16* hWr = h16 + (size_t)(b0 + bl) * NH + hb * 32 + hl;  // + buf*NB*NH

    // A-frag read geometry
    const int arow = lane & 15;
    const int aq = (lane >> 4) * 16;     // byte offset of 16B chunk within 64B k-block
    const int aswz = (arow & 7) << 4;

    // ---- prologue: stage w16[t=0] into wLDS[0] ----
    {
        const char* wsrc = (const char*)(w16 + (size_t)b0 * ND);
        const intx4 wd = *(const intx4*)(wsrc + tid * 16);
        const int wr = tid >> 5;
        *(intx4*)(smem + 16384 + ((tid * 16) ^ ((wr & 7) << 4))) = wd;
    }
    __syncthreads();

    #pragma unroll 1
    for (int t = 0; t < NL; ++t) {
        const int cur = t & 1, nxt = (t + 1) & 1;

        // ---- (1) prefetch w16[t+1] (plain cached load; off h-critical-path) ----
        const int tp = (t + 1 < NL) ? t + 1 : t;
        const intx4 wpref = *(const intx4*)(
            (const char*)(w16 + ((size_t)tp * NB + b0) * ND) + tid * 16);

        // ---- (2) accC = w @ W_ih^T from wLDS[cur] (independent of h_t) ----
        floatx4 accC = {0.f, 0.f, 0.f, 0.f};
        #pragma unroll
        for (int kk = 0; kk < 8; ++kk) {
            const int waddr = 16384 + 8192 * cur + ((((arow << 9) + (kk << 6) + aq)) ^ aswz);
            const half8 a = *(const half8*)(smem + waddr);
            accC = __builtin_amdgcn_mfma_f32_16x16x32_f16(a, bihF[kk], accC, 0, 0, 0);
        }

        // ---- (3) poll group tags for step t (wave 0 only, raw sc0 sc1 loads) ----
        if (t > 0 && wid == 0) {
            const int* fp = flags + (m << 4) + (lane & 15);
            int v;
            do {
                asm volatile(
                    "global_load_dword %0, %1, off sc0 sc1\n\t"
                    "s_waitcnt vmcnt(0)"
                    : "=v"(v) : "v"(fp) : "memory");
            } while (!__all(v >= t));
        }
        __syncthreads();

        // ---- (4) load h16[t&1] (raw sc0 sc1) -> hLDS; w prefetch -> wLDS[nxt] ----
        {
            const char* hsrc = (const char*)(h16 + (size_t)cur * NB * NH + (size_t)b0 * NH);
            intx4 d0, d1;
            asm volatile(
                "global_load_dwordx4 %0, %2, off sc0 sc1\n\t"
                "global_load_dwordx4 %1, %3, off sc0 sc1\n\t"
                "s_waitcnt vmcnt(0)"
                : "=v"(d0), "=v"(d1)
                : "v"(hsrc + tid * 16), "v"(hsrc + tid * 16 + 8192) : "memory");
            const int r0 = tid >> 6;               // 1024B per row
            const int r1 = (tid + 512) >> 6;
            *(intx4*)(smem + ((tid * 16) ^ ((r0 & 7) << 4))) = d0;
            *(intx4*)(smem + ((tid * 16 + 8192) ^ ((r1 & 7) << 4))) = d1;
            const int wr = tid >> 5;               // 512B per row
            *(intx4*)(smem + 16384 + 8192 * nxt + ((tid * 16) ^ ((wr & 7) << 4))) = wpref;
        }
        __syncthreads();

        // ---- (5) h GEMM: K=512 with hi/lo split weights ----
        floatx4 accA = {0.f, 0.f, 0.f, 0.f};
        floatx4 accB = {0.f, 0.f, 0.f, 0.f};
        #pragma unroll
        for (int kk = 0; kk < 16; ++kk) {
            const int aaddr = ((arow << 10) + (kk << 6) + aq) ^ aswz;
            const half8 a = *(const half8*)(smem + aaddr);
            accA = __builtin_amdgcn_mfma_f32_16x16x32_f16(a, bhhH[kk], accA, 0, 0, 0);
            accB = __builtin_amdgcn_mfma_f32_16x16x32_f16(a, bhhL[kk], accB, 0, 0, 0);
        }
        const floatx4 f = (accA + accB) + accC;

        // ---- (6) exchange acc tiles through LDS ----
        {
            float* accL = (float*)(smem + 32768);
            const int colw = lane & 15, rowq = (lane >> 4) * 4;
            #pragma unroll
            for (int r = 0; r < 4; ++r)
                accL[wid * 256 + (rowq + r) * 16 + colw] = f[r];
        }
        __syncthreads();

        // ---- (7) LSTM cell (one (b, h_idx) per thread; c in register) ----
        float h2;
        {
            const float* accL = (const float*)(smem + 32768);
            const int hq = hl >> 4, cidx = hl & 15;
            const int off = bl * 16 + cidx;
            const float pi = accL[(0 + hq) * 256 + off] + bias_[0];
            const float pf = accL[(2 + hq) * 256 + off] + bias_[1];
            const float pg = accL[(4 + hq) * 256 + off] + bias_[2];
            const float po = accL[(6 + hq) * 256 + off] + bias_[3];
            const float si = 1.f / (1.f + __expf(-pi));
            const float sf = 1.f / (1.f + __expf(-pf));
            const float so = 1.f / (1.f + __expf(-po));
            float e2 = __expf(-2.f * fabsf(pg));
            float tg = (1.f - e2) / (1.f + e2);
            tg = (pg < 0.f) ? -tg : tg;
            c = sf * c + si * tg;
            float e2c = __expf(-2.f * fabsf(c));
            float tc = (1.f - e2c) / (1.f + e2c);
            tc = (c < 0.f) ? -tc : tc;
            h2 = so * tc;
            // h16 store (device-visible, raw sc0 sc1)
            const _Float16 hh = (_Float16)h2;
            const unsigned int hv = (unsigned int)__builtin_bit_cast(unsigned short, hh);
            const void* hp = hWr + (size_t)nxt * NB * NH;
            asm volatile("global_store_short %0, %1, off sc0 sc1"
                         :: "v"(hp), "v"(hv) : "memory");
        }

        // ---- (8) drain h stores only -> tag; hsOut AFTER tag (off critical path) ----
        if (t < NL - 1) {
            asm volatile("s_waitcnt vmcnt(0)" ::: "memory");
            __syncthreads();   // all waves' h16 stores committed
            if (tid == 0) {
                const int* tp2 = flags + (m << 4) + hb;
                const int tv = t + 1;
                asm volatile("global_store_dword %0, %1, off sc0 sc1"
                             :: "v"(tp2), "v"(tv) : "memory");
            }
        }
        hsOut[(size_t)t * NH] = h2;   // fire-and-forget HBM store
    }
}

extern "C" void kernel_launch(void* const* d_in, const int* in_sizes, int n_in,
                              void* d_out, int out_size, void* d_ws, size_t ws_size,
                              hipStream_t stream) {
    const float* x     = (const float*)d_in[0];
    const float* Wattn = (const float*)d_in[1];
    // d_in[2] = b_attn : provably unused (softmax shift invariance)
    const float* Wih   = (const float*)d_in[3];
    const float* Whh   = (const float*)d_in[4];
    const float* bih   = (const float*)d_in[5];
    const float* bhh   = (const float*)d_in[6];

    float* ws_out = (float*)d_out;                                 // [B][L][D]
    float* hs_out = ws_out + (size_t)NB * NL * ND;                 // [B][L][H]

    char* ws = (char*)d_ws;
    int*      flags = (int*)(ws + 0);                              // 1 KB
    float*    attn  = (float*)(ws + 4096);                         // 256 KB
    float*    xproj = (float*)(ws + 4096 + 262144);                // 256 KB
    _Float16* h16   = (_Float16*)(ws + 1048576);                   // 2 x 256 KB
    _Float16* whhHi = (_Float16*)(ws + 2097152);                   // 2 MB
    _Float16* whhLo = (_Float16*)(ws + 2097152 + 2097152);         // 2 MB
    _Float16* wih16 = (_Float16*)(ws + 6291456);                   // 1 MB
    _Float16* w16   = (_Float16*)(ws + 8388608);                   // 33.5 MB

    hipMemsetAsync(flags, 0, 4096, stream);
    hipMemsetAsync(h16, 0, (size_t)NB * NH * sizeof(_Float16), stream);  // buf0 = h(0)

    k_xproj  <<<16384, 256, 0, stream>>>(x, Wattn, xproj);
    k_softmax<<<256,   256, 0, stream>>>(xproj, attn);
    k_trans  <<<4096,  256, 0, stream>>>(x, attn, ws_out, w16);
    k_wsplit <<<4096,  256, 0, stream>>>(Whh, Wih, whhHi, whhLo, wih16);
    k_recur  <<<256,   512, 0, stream>>>(whhHi, whhLo, wih16, w16, bih, bhh,
                                         h16, flags, hs_out);
}

// Round 4
// 695.763 us; speedup vs baseline: 3.3171x; 1.0374x over previous
//
#include <hip/hip_runtime.h>
#include <hip/hip_fp16.h>

typedef _Float16 half8 __attribute__((ext_vector_type(8)));
typedef float floatx4 __attribute__((ext_vector_type(4)));
typedef int intx4 __attribute__((ext_vector_type(4)));

#define NB 256   // batch
#define ND 256   // D
#define NL 256   // L (time)
#define NH 512   // H

// ---------------- Kernel 1: x_proj[b,d] = sum_l x[b,d,l] * Wx[l] ----------------
__global__ void k_xproj(const float* __restrict__ x, const float* __restrict__ Wattn,
                        float* __restrict__ xproj) {
    __shared__ float wx[NL];
    const int tid = threadIdx.x;
    wx[tid] = Wattn[2 * NH + tid];   // blockDim = 256 == NL
    __syncthreads();
    const int wid = tid >> 6, lane = tid & 63;
    const int row = blockIdx.x * 4 + wid;          // row = b*ND + d, 65536 rows
    const float4 v = ((const float4*)(x + (size_t)row * NL))[lane];
    float s = v.x * wx[lane * 4] + v.y * wx[lane * 4 + 1] +
              v.z * wx[lane * 4 + 2] + v.w * wx[lane * 4 + 3];
    #pragma unroll
    for (int off = 32; off; off >>= 1) s += __shfl_down(s, off);
    if (lane == 0) xproj[row] = s;
}

// ---------------- Kernel 2: attn[b,:] = softmax(x_proj[b,:]) ----------------
__global__ void k_softmax(const float* __restrict__ xproj, float* __restrict__ attn) {
    const int b = blockIdx.x, tid = threadIdx.x;
    __shared__ float red[8];
    float v = xproj[b * ND + tid];
    float m = v;
    #pragma unroll
    for (int off = 32; off; off >>= 1) m = fmaxf(m, __shfl_down(m, off));
    const int wid = tid >> 6, lane = tid & 63;
    if (lane == 0) red[wid] = m;
    __syncthreads();
    if (tid == 0) {
        float mm = fmaxf(fmaxf(red[0], red[1]), fmaxf(red[2], red[3]));
        red[4] = mm;
    }
    __syncthreads();
    const float e = expf(v - red[4]);
    float s = e;
    #pragma unroll
    for (int off = 32; off; off >>= 1) s += __shfl_down(s, off);
    if (lane == 0) red[wid] = s;
    __syncthreads();
    if (tid == 0) red[5] = red[0] + red[1] + red[2] + red[3];
    __syncthreads();
    attn[b * ND + tid] = e / red[5];
}

// ---- Kernel 3: ws[b,t,d] = attn[b,d]*x[b,d,t] (fp32 out) ; w16[t,b,d] = fp16(same) ----
__global__ void k_trans(const float* __restrict__ x, const float* __restrict__ attn,
                        float* __restrict__ ws_out, _Float16* __restrict__ w16) {
    __shared__ float tile[64][65];
    const int bid = blockIdx.x;
    const int b = bid >> 4, ti = (bid >> 2) & 3, tj = bid & 3;
    const int tx = threadIdx.x & 63, ty = threadIdx.x >> 6;
    const int d0 = ti * 64, l0 = tj * 64;
    const float* xb = x + ((size_t)b * ND + d0) * NL + l0;
    #pragma unroll
    for (int r = ty; r < 64; r += 4) tile[r][tx] = xb[(size_t)r * NL + tx];
    __syncthreads();
    const float af = attn[b * ND + d0 + tx];
    #pragma unroll
    for (int r = ty; r < 64; r += 4) {
        const int tt = l0 + r;
        const float val = af * tile[tx][r];
        ws_out[((size_t)b * NL + tt) * ND + d0 + tx] = val;
        w16[((size_t)tt * NB + b) * ND + d0 + tx] = (_Float16)val;
    }
}

// ---------------- Kernel 4: weight conversion (hi/lo split for W_hh) ----------------
__global__ void k_wsplit(const float* __restrict__ Whh, const float* __restrict__ Wih,
                         _Float16* __restrict__ hi, _Float16* __restrict__ lo,
                         _Float16* __restrict__ wih16) {
    const int idx = blockIdx.x * 256 + threadIdx.x;   // 4096*256 = 1048576 = 4H*H
    const float w = Whh[idx];
    const _Float16 h = (_Float16)w;
    hi[idx] = h;
    lo[idx] = (_Float16)(w - (float)h);
    if (idx < 4 * NH * ND) wih16[idx] = (_Float16)Wih[idx];
}

// ---------------- Kernel 5: persistent LSTM recurrence ----------------
// grid = 256 wgs x 512 thr. wg (m = bid&15, hb = bid>>4):
//   rows b in [16m, 16m+16), gate cols j = g*512 + hb*32 + [0,32) for g=0..3
// group = 16 wgs sharing m.
// Sync: EPOCH-TAGGED exchange. h stored as u32 {epoch(t+1)<<16 | fp16 h}.
// Consumers poll-load their own slice until every word's epoch == t; the poll
// IS the data load (no producer drain, no tag, no separate load, no flags).
// Ring depth 2 is race-free: epoch t+2 production transitively happens-after
// all consumption of epoch t (each consumer must produce t+1 first).
__launch_bounds__(512, 2)
__global__ void k_recur(const _Float16* __restrict__ whhHi, const _Float16* __restrict__ whhLo,
                        const _Float16* __restrict__ wih16, const _Float16* __restrict__ w16,
                        const float* __restrict__ b_ih, const float* __restrict__ b_hh,
                        unsigned int* __restrict__ h32,   // [2][NB][NH] epoch-tagged
                        float* __restrict__ out_hs)       // [NB][NL][NH]
{
    __shared__ char smem[40960];
    // [0,16384)      : hLDS  [16][512] fp16, 16B-granule XOR swizzle
    // [16384,32768)  : wLDS  2 x [16][256] fp16 (double-buffered), same swizzle
    // [32768,40960)  : accL  float[8][16][16]
    const int tid = threadIdx.x;
    const int wid = tid >> 6, lane = tid & 63;
    const int bid = blockIdx.x;
    const int m = bid & 15, hb = bid >> 4;
    const int b0 = m * 16;
    const int gate = wid >> 1, half = wid & 1;
    const int jb = gate * 512 + hb * 32 + half * 16;

    // --- persistent B fragments (live across whole time loop) ---
    half8 bhhH[16], bhhL[16], bihF[8];
    const int bcol = jb + (lane & 15);
    const int krow = (lane >> 4) * 8;
    #pragma unroll
    for (int kk = 0; kk < 16; ++kk) {
        bhhH[kk] = *(const half8*)(whhHi + (size_t)bcol * NH + kk * 32 + krow);
        bhhL[kk] = *(const half8*)(whhLo + (size_t)bcol * NH + kk * 32 + krow);
    }
    #pragma unroll
    for (int kk = 0; kk < 8; ++kk)
        bihF[kk] = *(const half8*)(wih16 + (size_t)bcol * ND + kk * 32 + krow);

    // --- cell-phase thread mapping: one (b, h_idx) per thread ---
    const int bl = tid >> 5, hl = tid & 31;
    float bias_[4];
    #pragma unroll
    for (int g = 0; g < 4; ++g) {
        const int j = g * 512 + hb * 32 + hl;
        bias_[g] = b_ih[j] + b_hh[j];
    }
    float c = 0.f;
    float* hsOut = out_hs + (size_t)(b0 + bl) * NL * NH + hb * 32 + hl;
    unsigned int* hWr = h32 + (size_t)(b0 + bl) * NH + hb * 32 + hl;  // + buf*NB*NH

    // A-frag read geometry
    const int arow = lane & 15;
    const int aq = (lane >> 4) * 16;     // byte offset of 16B chunk within 64B k-block
    const int aswz = (arow & 7) << 4;

    // poll/stage geometry: thread -> (row hrow, 16 h-elems at hcol16)
    const int hrow = tid >> 5;
    const int hcol16 = (tid & 31) * 16;
    const int hbase = (hrow << 10) + (tid & 31) * 32;   // LDS byte addr of 32B slot
    const int hswz = (hrow & 7) << 4;

    // ---- prologue: stage w16[t=0] into wLDS[0] ----
    {
        const char* wsrc = (const char*)(w16 + (size_t)b0 * ND);
        const intx4 wd = *(const intx4*)(wsrc + tid * 16);
        const int wr = tid >> 5;
        *(intx4*)(smem + 16384 + ((tid * 16) ^ ((wr & 7) << 4))) = wd;
    }
    __syncthreads();

    #pragma unroll 1
    for (int t = 0; t < NL; ++t) {
        const int cur = t & 1, nxt = (t + 1) & 1;

        // ---- (1) prefetch w16[t+1] (plain cached load; off h-critical-path) ----
        const int tp = (t + 1 < NL) ? t + 1 : t;
        const intx4 wpref = *(const intx4*)(
            (const char*)(w16 + ((size_t)tp * NB + b0) * ND) + tid * 16);

        // ---- (2) accC = w @ W_ih^T from wLDS[cur] (independent of h_t) ----
        floatx4 accC = {0.f, 0.f, 0.f, 0.f};
        #pragma unroll
        for (int kk = 0; kk < 8; ++kk) {
            const int waddr = 16384 + 8192 * cur + ((((arow << 9) + (kk << 6) + aq)) ^ aswz);
            const half8 a = *(const half8*)(smem + waddr);
            accC = __builtin_amdgcn_mfma_f32_16x16x32_f16(a, bihF[kk], accC, 0, 0, 0);
        }

        // ---- (3) poll-load h_t (epoch-tagged, per-thread) & stage to LDS ----
        if (t > 0) {
            const unsigned int* hsrc =
                h32 + (size_t)cur * NB * NH + (size_t)(b0 + hrow) * NH + hcol16;
            intx4 q0, q1, q2, q3;
            const unsigned int et = (unsigned int)t;
            while (true) {
                asm volatile(
                    "global_load_dwordx4 %0, %4, off sc0 sc1\n\t"
                    "global_load_dwordx4 %1, %4, off offset:16 sc0 sc1\n\t"
                    "global_load_dwordx4 %2, %4, off offset:32 sc0 sc1\n\t"
                    "global_load_dwordx4 %3, %4, off offset:48 sc0 sc1\n\t"
                    "s_waitcnt vmcnt(0)"
                    : "=v"(q0), "=v"(q1), "=v"(q2), "=v"(q3)
                    : "v"(hsrc) : "memory");
                bool ok = true;
                #pragma unroll
                for (int i = 0; i < 4; ++i) {
                    ok &= (((unsigned int)q0[i]) >> 16) == et;
                    ok &= (((unsigned int)q1[i]) >> 16) == et;
                    ok &= (((unsigned int)q2[i]) >> 16) == et;
                    ok &= (((unsigned int)q3[i]) >> 16) == et;
                }
                if (ok) break;
            }
            // pack 16 tagged words -> 16 fp16 (2 x 16B)
            intx4 d0, d1;
            d0[0] = (q0[0] & 0xffff) | (q0[1] << 16);
            d0[1] = (q0[2] & 0xffff) | (q0[3] << 16);
            d0[2] = (q1[0] & 0xffff) | (q1[1] << 16);
            d0[3] = (q1[2] & 0xffff) | (q1[3] << 16);
            d1[0] = (q2[0] & 0xffff) | (q2[1] << 16);
            d1[1] = (q2[2] & 0xffff) | (q2[3] << 16);
            d1[2] = (q3[0] & 0xffff) | (q3[1] << 16);
            d1[3] = (q3[2] & 0xffff) | (q3[3] << 16);
            *(intx4*)(smem + (hbase ^ hswz)) = d0;
            *(intx4*)(smem + ((hbase + 16) ^ hswz)) = d1;
        } else {
            const intx4 z = {0, 0, 0, 0};
            *(intx4*)(smem + (hbase ^ hswz)) = z;
            *(intx4*)(smem + ((hbase + 16) ^ hswz)) = z;
        }
        // stage w prefetch -> wLDS[nxt]
        {
            const int wr = tid >> 5;
            *(intx4*)(smem + 16384 + 8192 * nxt + ((tid * 16) ^ ((wr & 7) << 4))) = wpref;
        }
        __syncthreads();

        // ---- (4) h GEMM: K=512 with hi/lo split weights ----
        floatx4 accA = {0.f, 0.f, 0.f, 0.f};
        floatx4 accB = {0.f, 0.f, 0.f, 0.f};
        #pragma unroll
        for (int kk = 0; kk < 16; ++kk) {
            const int aaddr = ((arow << 10) + (kk << 6) + aq) ^ aswz;
            const half8 a = *(const half8*)(smem + aaddr);
            accA = __builtin_amdgcn_mfma_f32_16x16x32_f16(a, bhhH[kk], accA, 0, 0, 0);
            accB = __builtin_amdgcn_mfma_f32_16x16x32_f16(a, bhhL[kk], accB, 0, 0, 0);
        }
        const floatx4 f = (accA + accB) + accC;

        // ---- (5) exchange acc tiles through LDS ----
        {
            float* accL = (float*)(smem + 32768);
            const int colw = lane & 15, rowq = (lane >> 4) * 4;
            #pragma unroll
            for (int r = 0; r < 4; ++r)
                accL[wid * 256 + (rowq + r) * 16 + colw] = f[r];
        }
        __syncthreads();

        // ---- (6) LSTM cell (one (b, h_idx) per thread; c in register) ----
        float h2;
        {
            const float* accL = (const float*)(smem + 32768);
            const int hq = hl >> 4, cidx = hl & 15;
            const int off = bl * 16 + cidx;
            const float pi = accL[(0 + hq) * 256 + off] + bias_[0];
            const float pf = accL[(2 + hq) * 256 + off] + bias_[1];
            const float pg = accL[(4 + hq) * 256 + off] + bias_[2];
            const float po = accL[(6 + hq) * 256 + off] + bias_[3];
            const float si = 1.f / (1.f + __expf(-pi));
            const float sf = 1.f / (1.f + __expf(-pf));
            const float so = 1.f / (1.f + __expf(-po));
            float e2 = __expf(-2.f * fabsf(pg));
            float tg = (1.f - e2) / (1.f + e2);
            tg = (pg < 0.f) ? -tg : tg;
            c = sf * c + si * tg;
            float e2c = __expf(-2.f * fabsf(c));
            float tc = (1.f - e2c) / (1.f + e2c);
            tc = (c < 0.f) ? -tc : tc;
            h2 = so * tc;
            // epoch-tagged h store (fire-and-forget, device-visible)
            const _Float16 hh = (_Float16)h2;
            const unsigned int hv =
                ((unsigned int)(t + 1) << 16) |
                (unsigned int)__builtin_bit_cast(unsigned short, hh);
            const void* hp = hWr + (size_t)nxt * NB * NH;
            asm volatile("global_store_dword %0, %1, off sc0 sc1"
                         :: "v"(hp), "v"(hv) : "memory");
        }
        hsOut[(size_t)t * NH] = h2;   // fire-and-forget HBM store
    }
}

extern "C" void kernel_launch(void* const* d_in, const int* in_sizes, int n_in,
                              void* d_out, int out_size, void* d_ws, size_t ws_size,
                              hipStream_t stream) {
    const float* x     = (const float*)d_in[0];
    const float* Wattn = (const float*)d_in[1];
    // d_in[2] = b_attn : provably unused (softmax shift invariance)
    const float* Wih   = (const float*)d_in[3];
    const float* Whh   = (const float*)d_in[4];
    const float* bih   = (const float*)d_in[5];
    const float* bhh   = (const float*)d_in[6];

    float* ws_out = (float*)d_out;                                 // [B][L][D]
    float* hs_out = ws_out + (size_t)NB * NL * ND;                 // [B][L][H]

    char* ws = (char*)d_ws;
    float*    attn  = (float*)(ws + 4096);                         // 256 KB
    float*    xproj = (float*)(ws + 4096 + 262144);                // 256 KB
    unsigned int* h32 = (unsigned int*)(ws + 1048576);             // 2 x 512 KB tagged
    _Float16* whhHi = (_Float16*)(ws + 2097152);                   // 2 MB
    _Float16* whhLo = (_Float16*)(ws + 2097152 + 2097152);         // 2 MB
    _Float16* wih16 = (_Float16*)(ws + 6291456);                   // 1 MB
    _Float16* w16   = (_Float16*)(ws + 8388608);                   // 33.5 MB

    k_xproj  <<<16384, 256, 0, stream>>>(x, Wattn, xproj);
    k_softmax<<<256,   256, 0, stream>>>(xproj, attn);
    k_trans  <<<4096,  256, 0, stream>>>(x, attn, ws_out, w16);
    k_wsplit <<<4096,  256, 0, stream>>>(Whh, Wih, whhHi, whhLo, wih16);
    k_recur  <<<256,   512, 0, stream>>>(whhHi, whhLo, wih16, w16, bih, bhh,
                                         h32, hs_out);
}